// Round 1
// baseline (149.335 us; speedup 1.0000x reference)
//
#include <hip/hip_runtime.h>
#include <hip/hip_bf16.h>

typedef __attribute__((ext_vector_type(4))) float f32x4;
typedef __attribute__((ext_vector_type(4))) short s16x4;
typedef __attribute__((ext_vector_type(4))) unsigned short u16x4;

#define MFMA16(a, b, c) __builtin_amdgcn_mfma_f32_16x16x16bf16_1k((a), (b), (c), 0, 0, 0)

static __device__ __forceinline__ short f2bf(float f) {
  union { float f; unsigned u; } v; v.f = f;
  unsigned r = v.u + 0x7fffu + ((v.u >> 16) & 1u);
  return (short)(r >> 16);
}

// B=8, S=2048, E=1024, H=64. Scale E^-0.5 = 1/32 folded into Wq.
// ws layout: Wt[192][1024] bf16 | q[8][2048][64] bf16 | k[8][2048][64] bf16 | vt[8][64][2048] bf16

// ---------- Kernel 0: W transpose/convert. Wt rows 0-63 = Wq*(1/32), 64-127 = Wk, 128-191 = Wv ----------
__global__ __launch_bounds__(256) void wt_kernel(const float* __restrict__ Wq,
                                                 const float* __restrict__ Wk,
                                                 const float* __restrict__ Wv,
                                                 unsigned short* __restrict__ Wt) {
  int n = blockIdx.x;                       // 0..191 output row
  const float* W = (n < 64) ? Wq : (n < 128 ? Wk : Wv);
  float scl = (n < 64) ? 0.03125f : 1.0f;
  int col = n & 63;
  for (int k = threadIdx.x; k < 1024; k += 256)
    Wt[n * 1024 + k] = (unsigned short)f2bf(W[k * 64 + col] * scl);
}

// ---------- Kernel 1: fused QKV projection via MFMA ----------
// Block = 4 waves, 64 rows of x. Wave w computes N-tiles {3w..3w+2} of 12 (192 cols: q|k|v).
__global__ __launch_bounds__(256) void proj_kernel(const float* __restrict__ x,
                                                   const unsigned short* __restrict__ Wt,
                                                   unsigned short* __restrict__ qb,
                                                   unsigned short* __restrict__ kb,
                                                   unsigned short* __restrict__ vtb) {
  const int wid = threadIdx.x >> 6;
  const int lane = threadIdx.x & 63;
  const int l15 = lane & 15, g = lane >> 4;
  const int m0 = blockIdx.x * 64;

  f32x4 acc[4][3];
#pragma unroll
  for (int i = 0; i < 4; i++)
#pragma unroll
    for (int j = 0; j < 3; j++) acc[i][j] = (f32x4){0.f, 0.f, 0.f, 0.f};

  for (int k0 = 0; k0 < 1024; k0 += 16) {
    s16x4 a[4];
#pragma unroll
    for (int mt = 0; mt < 4; mt++) {
      const f32x4 xf = *(const f32x4*)(x + (size_t)(m0 + mt * 16 + l15) * 1024 + k0 + 4 * g);
      s16x4 t;
      t[0] = f2bf(xf[0]); t[1] = f2bf(xf[1]); t[2] = f2bf(xf[2]); t[3] = f2bf(xf[3]);
      a[mt] = t;
    }
    s16x4 bfr[3];
#pragma unroll
    for (int j = 0; j < 3; j++) {
      int n = 48 * wid + 16 * j + l15;
      bfr[j] = *(const s16x4*)(Wt + n * 1024 + k0 + 4 * g);
    }
#pragma unroll
    for (int mt = 0; mt < 4; mt++)
#pragma unroll
      for (int j = 0; j < 3; j++)
        acc[mt][j] = MFMA16(a[mt], bfr[j], acc[mt][j]);
  }

#pragma unroll
  for (int mt = 0; mt < 4; mt++) {
    int m = m0 + mt * 16 + 4 * g;          // first of this lane's 4 output rows
    int b = m >> 11, s = m & 2047;
#pragma unroll
    for (int j = 0; j < 3; j++) {
      int ncol = 48 * wid + 16 * j;
      int mat = ncol >> 6;                 // 0=q, 1=k, 2=v
      int n = (ncol & 63) + l15;
      if (mat < 2) {
        unsigned short* dst = (mat == 0 ? qb : kb) + ((size_t)b * 2048 + s) * 64 + n;
#pragma unroll
        for (int r = 0; r < 4; r++) dst[(size_t)r * 64] = (unsigned short)f2bf(acc[mt][j][r]);
      } else {                             // v stored transposed: vt[b][d][s]
        u16x4 pv;
#pragma unroll
        for (int r = 0; r < 4; r++) pv[r] = (unsigned short)f2bf(acc[mt][j][r]);
        *(u16x4*)(vtb + ((size_t)b * 64 + n) * 2048 + s) = pv;
      }
    }
  }
}

// ---------- Kernel 2: causal flash attention ----------
// Block = 2 waves. Wave handles q-tiles t and 127-t (16 rows each) -> balanced 129 kv-steps.
// St = mfma(K_frag, Q_frag): St[kv][q] with C-layout kv = 4g+reg, q = lane&15.
// P (exp(St - m)) in the SAME registers is directly the B-operand for PV MFMA.
__global__ __launch_bounds__(128) void attn_kernel(const unsigned short* __restrict__ qb,
                                                   const unsigned short* __restrict__ kb,
                                                   const unsigned short* __restrict__ vtb,
                                                   float* __restrict__ out) {
  const int wid = threadIdx.x >> 6;
  const int lane = threadIdx.x & 63;
  const int l15 = lane & 15, g = lane >> 4;
  const int b = blockIdx.x >> 5;
  const int v = (blockIdx.x & 31) * 2 + wid;  // 0..63

  const unsigned short* q = qb + (size_t)b * 2048 * 64;
  const unsigned short* k = kb + (size_t)b * 2048 * 64;
  const unsigned short* vt = vtb + (size_t)b * 64 * 2048;
  float* o = out + (size_t)b * 2048 * 64;

  for (int pass = 0; pass < 2; pass++) {
    const int t = pass ? (127 - v) : v;
    const int q0 = t * 16;

    s16x4 qf[4];
#pragma unroll
    for (int d = 0; d < 4; d++)
      qf[d] = *(const s16x4*)(q + (size_t)(q0 + l15) * 64 + d * 16 + 4 * g);

    f32x4 ot[4];
#pragma unroll
    for (int d = 0; d < 4; d++) ot[d] = (f32x4){0.f, 0.f, 0.f, 0.f};
    float mcur = -1e30f, lsum = 0.f;

    for (int kv0 = 0; kv0 <= q0; kv0 += 16) {
      f32x4 st = (f32x4){0.f, 0.f, 0.f, 0.f};
#pragma unroll
      for (int d = 0; d < 4; d++) {
        s16x4 kf = *(const s16x4*)(k + (size_t)(kv0 + l15) * 64 + d * 16 + 4 * g);
        st = MFMA16(kf, qf[d], st);
      }
      if (kv0 == q0) {                      // diagonal tile: mask kv > q
#pragma unroll
        for (int r = 0; r < 4; r++)
          if (4 * g + r > l15) st[r] = -1e30f;
      }
      float mx = fmaxf(fmaxf(st[0], st[1]), fmaxf(st[2], st[3]));
      mx = fmaxf(mx, __shfl_xor(mx, 16));
      mx = fmaxf(mx, __shfl_xor(mx, 32));
      const float mnew = fmaxf(mcur, mx);
      const float fac = exp2f((mcur - mnew) * 1.44269504088896340736f);
      f32x4 p;
      float ps = 0.f;
#pragma unroll
      for (int r = 0; r < 4; r++) {
        p[r] = exp2f((st[r] - mnew) * 1.44269504088896340736f);
        ps += p[r];
      }
      ps += __shfl_xor(ps, 16);
      ps += __shfl_xor(ps, 32);
      lsum = lsum * fac + ps;
      s16x4 pf;
#pragma unroll
      for (int r = 0; r < 4; r++) pf[r] = f2bf(p[r]);
#pragma unroll
      for (int dt = 0; dt < 4; dt++) {
#pragma unroll
        for (int r = 0; r < 4; r++) ot[dt][r] *= fac;
        s16x4 vf = *(const s16x4*)(vt + (size_t)(dt * 16 + l15) * 2048 + kv0 + 4 * g);
        ot[dt] = MFMA16(vf, pf, ot[dt]);
      }
      mcur = mnew;
    }

    const float inv = 1.0f / lsum;
#pragma unroll
    for (int dt = 0; dt < 4; dt++) {
      f32x4 r;
#pragma unroll
      for (int i = 0; i < 4; i++) r[i] = ot[dt][i] * inv;
      *(f32x4*)(o + (size_t)(q0 + l15) * 64 + dt * 16 + 4 * g) = r;
    }
  }
}

extern "C" void kernel_launch(void* const* d_in, const int* in_sizes, int n_in,
                              void* d_out, int out_size, void* d_ws, size_t ws_size,
                              hipStream_t stream) {
  const float* x = (const float*)d_in[0];
  const float* Wk = (const float*)d_in[1];
  const float* Wq = (const float*)d_in[2];
  const float* Wv = (const float*)d_in[3];
  float* out = (float*)d_out;

  char* ws = (char*)d_ws;
  unsigned short* Wt = (unsigned short*)ws;                              // 192*1024*2 = 393216 B
  unsigned short* qbuf = (unsigned short*)(ws + 393216);                 // 2 MiB
  unsigned short* kbuf = (unsigned short*)(ws + 393216 + 2097152);       // 2 MiB
  unsigned short* vtbuf = (unsigned short*)(ws + 393216 + 2 * 2097152);  // 2 MiB

  wt_kernel<<<192, 256, 0, stream>>>(Wq, Wk, Wv, Wt);
  proj_kernel<<<256, 256, 0, stream>>>(x, Wt, qbuf, kbuf, vtbuf);
  attn_kernel<<<256, 128, 0, stream>>>(qbuf, kbuf, vtbuf, out);
}